// Round 3
// baseline (149.206 us; speedup 1.0000x reference)
//
#include <hip/hip_runtime.h>
#include <hip/hip_bf16.h>
#include <stdint.h>

// ===================================================================
// PriorLayer online BP scan, round 3.
// R2 post-mortem: per-step time was ~2.0us in BOTH R1 and R2 — the
// barrier restructure didn't touch the real tail: logs + 2 dependent
// ds_bpermute shuffles + partial-write AFTER the MFMAs, all drained by
// lgkmcnt(0) at the step barrier (~500-700cyc serial tail), plus SW-RNE
// bf16 converts. HBM floor is ~125MB/6.3TBs ~= 20us; we were at 56.
// R3 changes:
//  - Entropy tail computed from qp (step-1) at the TOP of each body, so
//    its log/shuffle latency overlaps the current step's MFMA phase.
//    Finalize (Z,L reduce + normalized out + H) moves to step-2 (qpp).
//    Ring: q -> qp -> qpp; pZL partials double-buffered by parity.
//  - 2^-6 anti-growth rescale folded into A (exact exponent shift in
//    bf16) — kills 8 muls/step.
//  - State bf16 pack via +0x8000 round-half-up + v_perm_b32 byte pack
//    (12 instr vs ~40 for SW-RNE __float2bfloat16). Bias is common-mode
//    across the state vector -> removed by normalization.
//  - BURN 12 -> 8: R1(BURN=32) and R2(BURN=12) gave identical absmax
//    0.03125 => error floor is bf16 state quantization, not chunk
//    truncation (contraction ~0.04/step, 0.04^8 ~ 7e-12).
// ===================================================================

#define DIM   256
#define SEQ   65536
#define G     16                    // chunks (MFMA columns) per block
#define NBLK  256                   // 1 block / CU
#define CLEN  (SEQ / (G * NBLK))    // 16 output steps per chunk
#define BURN  8
#define STEPS (BURN + CLEN)         // 24 (even — loop pairing relies on it)
#define NW    8
#define TPB   (NW * 64)
#define SROW  264                   // padded LDS row stride (bf16 elems)

typedef short bf16x8 __attribute__((ext_vector_type(8)));
typedef float f32x4  __attribute__((ext_vector_type(4)));
typedef float f32x2  __attribute__((ext_vector_type(2)));

static __device__ __forceinline__ unsigned short f2bf(float x) {
  __hip_bfloat16 h = __float2bfloat16(x);
  return *reinterpret_cast<unsigned short*>(&h);
}

// LDS-only barrier: drain lgkm (ds ops) but NOT vmcnt — global stores
// and prefetch loads stay in flight across the step boundary.
static __device__ __forceinline__ void lds_barrier() {
  asm volatile("s_waitcnt lgkmcnt(0)" ::: "memory");
  __builtin_amdgcn_s_barrier();
}

// pack two f32 to two bf16 (round-half-up): dword = [hi16(a), hi16(b)]
static __device__ __forceinline__ uint32_t pack_bf2(float a, float b) {
  uint32_t ua = __float_as_uint(a) + 0x8000u;
  uint32_t ub = __float_as_uint(b) + 0x8000u;
  // byte sel (LSB first): ua.b2, ua.b3, ub.b2, ub.b3 ; src0=ub, src1=ua
  return __builtin_amdgcn_perm(ub, ua, 0x07060302u);
}

__global__ __launch_bounds__(TPB)
void prior_scan_kernel(const float* __restrict__ probs,
                       const float* __restrict__ tp,
                       float* __restrict__ out) {
  __shared__ __attribute__((aligned(16))) short S_T[2][G][SROW];
  __shared__ f32x2 pZL[2][NW][G];   // per-wave {sum q, sum q ln q} per col

  const int tid  = threadIdx.x;
  const int w    = tid >> 6;
  const int lane = tid & 63;
  const int n    = lane & 15;       // MFMA col = chunk within block
  const int quad = lane >> 4;
  const int c0   = blockIdx.x * G + n;          // this lane's chunk id
  const int r0 = (2 * w) * 16 + quad * 4;       // C/D row base, tile 0
  const int r1 = (2 * w + 1) * 16 + quad * 4;   // tile 1

  // ---- A-fragments of T * 2^-6 (scale exact in bf16; prevents state
  //      overflow so the per-step state write needs no rescale mul)
  bf16x8 A[2][8];
#pragma unroll
  for (int rt = 0; rt < 2; rt++) {
    const int row = (2 * w + rt) * 16 + n;
#pragma unroll
    for (int kb = 0; kb < 8; kb++) {
      const float* p = tp + row * DIM + kb * 32 + quad * 8;
      f32x4 f0 = *reinterpret_cast<const f32x4*>(p);
      f32x4 f1 = *reinterpret_cast<const f32x4*>(p + 4);
      bf16x8 a;
#pragma unroll
      for (int j = 0; j < 4; j++) {
        a[j]     = (short)f2bf(f0[j] * 0.015625f);
        a[4 + j] = (short)f2bf(f1[j] * 0.015625f);
      }
      A[rt][kb] = a;
    }
  }

  // ---- init state buf 0 = uniform (any positive constant; scale-free)
  for (int i = tid; i < G * SROW; i += TPB)
    (&S_T[0][0][0])[i] = (short)0x3B80;

  auto loadp = [&](int s, int rbase) -> f32x4 {
    int t = c0 * CLEN - BURN + s;
    if (t < 0) t = 0;               // value unused while state clamped
    return *reinterpret_cast<const f32x4*>(probs + (size_t)t * DIM + rbase);
  };

  f32x4 pf[2][2];
  pf[0][0] = loadp(0, r0); pf[0][1] = loadp(0, r1);
  pf[1][0] = loadp(1, r0); pf[1][1] = loadp(1, r1);

  lds_barrier();

  float q[2][4], qp[2][4], qpp[2][4];

  // body(step): recurrence for `step`; entropy partials for step-1;
  // finalize (normalize + H) for step-2. cur=step&1, nxt=cur^1.
  auto body = [&](int step, int cur, int nxt) {
    // ---- entropy partials of step-1 (from qp): issued FIRST so the
    //      log + bpermute latency overlaps the MFMA phase below.
    if (step >= 1 && step <= STEPS) {
      float sz = 0.f, sl = 0.f;
#pragma unroll
      for (int rt = 0; rt < 2; rt++)
#pragma unroll
        for (int v = 0; v < 4; v++) {
          float qq = qp[rt][v];
          sz += qq;
          sl += qq * __logf(qq + 1e-30f);
        }
      sz += __shfl_xor(sz, 16); sz += __shfl_xor(sz, 32);
      sl += __shfl_xor(sl, 16); sl += __shfl_xor(sl, 32);
      if (lane < 16) pZL[nxt][w][n] = f32x2{sz, sl};  // slot (step-1)&1
    }

    // ---- recurrence: acc = (2^-6 T) @ u ; q = acc o p
    if (step < STEPS) {
      f32x4 acc0 = {0.f, 0.f, 0.f, 0.f}, acc1 = {0.f, 0.f, 0.f, 0.f};
#pragma unroll
      for (int kb = 0; kb < 8; kb++) {
        bf16x8 b = *reinterpret_cast<const bf16x8*>(
            &S_T[cur][n][kb * 32 + quad * 8]);
        acc0 = __builtin_amdgcn_mfma_f32_16x16x32_bf16(A[0][kb], b, acc0, 0, 0, 0);
        acc1 = __builtin_amdgcn_mfma_f32_16x16x32_bf16(A[1][kb], b, acc1, 0, 0, 0);
      }
      const int t = c0 * CLEN - BURN + step;
#pragma unroll
      for (int rt = 0; rt < 2; rt++) {
        f32x4 p = pf[cur][rt];
        f32x4 a = rt ? acc1 : acc0;
#pragma unroll
        for (int v = 0; v < 4; v++) q[rt][v] = a[v] * p[v];
      }
      // state write (bf16 round-half-up pack; clamp pre-start chunks)
#pragma unroll
      for (int rt = 0; rt < 2; rt++) {
        uint2 sp;
        if (t < 0) {
          sp.x = sp.y = 0x3B803B80u;
        } else {
          sp.x = pack_bf2(q[rt][0], q[rt][1]);
          sp.y = pack_bf2(q[rt][2], q[rt][3]);
        }
        *reinterpret_cast<uint2*>(&S_T[nxt][n][rt ? r1 : r0]) = sp;
      }
    }

    // ---- finalize step-2: reduce partials (slot (step-2)&1 == cur),
    //      write normalized probs + entropy. Off the serial chain.
    if (step >= BURN + 2) {
      float Z = 0.f, L = 0.f;
#pragma unroll
      for (int ww = 0; ww < NW; ww++) {
        f32x2 v = pZL[cur][ww][n];
        Z += v[0]; L += v[1];
      }
      const float zi = __builtin_amdgcn_rcpf(Z);
      const int t2 = c0 * CLEN + (step - 2 - BURN);
#pragma unroll
      for (int rt = 0; rt < 2; rt++) {
        f32x4 o;
#pragma unroll
        for (int v = 0; v < 4; v++) o[v] = qpp[rt][v] * zi;
        *reinterpret_cast<f32x4*>(out + (size_t)t2 * DIM + (rt ? r1 : r0)) = o;
      }
      if (tid < 16)                 // n == tid for these lanes
        out[(size_t)SEQ * DIM + t2] = __logf(Z) - L * zi;
    }

    // ---- ring shift + prefetch step+2 into consumed slot
    if (step < STEPS) {
#pragma unroll
      for (int rt = 0; rt < 2; rt++)
#pragma unroll
        for (int v = 0; v < 4; v++) { qpp[rt][v] = qp[rt][v]; qp[rt][v] = q[rt][v]; }
      int ps = step + 2; if (ps > STEPS - 1) ps = STEPS - 1;
      pf[cur][0] = loadp(ps, r0);
      pf[cur][1] = loadp(ps, r1);
    } else {
#pragma unroll
      for (int rt = 0; rt < 2; rt++)
#pragma unroll
        for (int v = 0; v < 4; v++) qpp[rt][v] = qp[rt][v];
    }
    if (step <= STEPS) lds_barrier();
  };

  // loop covers step = 0 .. STEPS+1 (two reduction-only tail bodies)
  for (int s = 0; s <= STEPS; s += 2) {
    body(s, 0, 1);
    body(s + 1, 1, 0);
  }
}

extern "C" void kernel_launch(void* const* d_in, const int* in_sizes, int n_in,
                              void* d_out, int out_size, void* d_ws, size_t ws_size,
                              hipStream_t stream) {
  const float* probs = (const float*)d_in[0];   // (65536, 256)
  const float* tp    = (const float*)d_in[1];   // (256, 256)
  float* out         = (float*)d_out;           // 65536*256 probs + 65536 H

  hipLaunchKernelGGL(prior_scan_kernel, dim3(NBLK), dim3(TPB), 0, stream,
                     probs, tp, out);
}